// Round 2
// baseline (156218.042 us; speedup 1.0000x reference)
//
#include <hip/hip_runtime.h>
#include <stdint.h>

// ---------------------------------------------------------------------------
// StabilizedNeuralODE: 6-stage RK over 511 steps of a 128->512->512->128 MLP
// vector field (+ y@A.T). Inputs/outputs fp32; internal GEMMs bf16 MFMA with
// fp32 accumulation; y / k / RK combine stay fp32 (tolerance is 2% of |ref|).
//
// Design: 32 groups x 8 WGs (256 WGs, 1 per CU, cooperative launch).
//  - Group g owns batch rows [16g, 16g+16) for the entire trajectory.
//  - WG p of a group keeps bf16 weight slices LDS-resident (~100 KB):
//      w1 rows [64p,64p+64), w2 rows [64p,64p+64), w3/A rows [16p,16p+16)
//  - Per RK stage: 3 phases (h1, h2, k) with an agent-scope group barrier
//    after each; activations bounce through an L2-resident workspace (bf16,
//    k partial sums fp32).
// MFMA: v_mfma_f32_16x16x32_bf16. A-frag: A[m=lane&15][k=quad*8+j];
// B-frag: B[n=lane&15][k=quad*8+j] (weights are [N][K] = B^T layout);
// C/D: n=lane&15, m=quad*4+reg.
// LDS rows padded +8 bf16 (stride 520/136) -> 2 lanes/bank on b128 (free).
// ---------------------------------------------------------------------------

#define Dd 128
#define Ww 512
#define Bb 512
#define Tt 512
#define NSTEP 511
#define NGRP 32
#define PWG 8
#define MROW 16
#define NTHR 256

// LDS layout (ushort element offsets)
#define OFF_W2 0        // 64 x 520
#define OFF_W1 33280    // 64 x 136
#define OFF_W3 41984    // 16 x 520
#define OFF_A  50304    // 16 x 136
#define OFF_H1 52480    // 16 x 520
#define OFF_H2 60800    // 16 x 520
#define OFF_Y  69120    // 16 x 136
#define FREG_BYTE 142592
#define SMEM_BYTES 147456

typedef __attribute__((ext_vector_type(8))) __bf16 bf16x8;
typedef __attribute__((ext_vector_type(4))) float f32x4;

__device__ __forceinline__ unsigned short f2b(float f) {
  union { float f; unsigned int u; } v; v.f = f;
  return (unsigned short)((v.u + 0x7fffu + ((v.u >> 16) & 1u)) >> 16);
}
__device__ __forceinline__ void st4bf(unsigned short* dst, float4 v) {
  union { unsigned short u[4]; uint2 q; } p;
  p.u[0] = f2b(v.x); p.u[1] = f2b(v.y); p.u[2] = f2b(v.z); p.u[3] = f2b(v.w);
  *(uint2*)dst = p.q;
}
__device__ __forceinline__ float fast_tanh(float x) {
  x = fminf(fmaxf(x, -15.f), 15.f);
  float e = __expf(2.f * x);
  return (e - 1.f) / (e + 1.f);
}

// Agent-scope group barrier (8 WGs). Monotone targets; relaxed spin + one
// acquire load. Returns false (uniformly) on spin-out so the kernel can bail
// loudly instead of hanging.
__device__ __forceinline__ bool group_barrier(unsigned* bar, unsigned target,
                                              int* okf) {
  __syncthreads();
  if (threadIdx.x == 0) {
    int ok = 1;
    unsigned r = __hip_atomic_fetch_add(&bar[0], 1u, __ATOMIC_ACQ_REL,
                                        __HIP_MEMORY_SCOPE_AGENT) + 1u;
    if (r == target) {
      __hip_atomic_store(&bar[1], target, __ATOMIC_RELEASE,
                         __HIP_MEMORY_SCOPE_AGENT);
    } else {
      unsigned spins = 0;
      while (__hip_atomic_load(&bar[1], __ATOMIC_RELAXED,
                               __HIP_MEMORY_SCOPE_AGENT) < target) {
        __builtin_amdgcn_s_sleep(2);
        if (++spins > (1u << 20)) { ok = 0; break; }
      }
      (void)__hip_atomic_load(&bar[1], __ATOMIC_ACQUIRE,
                              __HIP_MEMORY_SCOPE_AGENT);
    }
    *okf = ok;
  }
  __syncthreads();
  return *okf != 0;
}

__global__ void init_ws_kernel(unsigned* ws) {
  ws[threadIdx.x] = 0u;  // zero barrier region (4096 B), launched <<<1,1024>>>
}

__global__ void __launch_bounds__(NTHR, 1)
ode_kernel(const float* __restrict__ ts,
           const float* __restrict__ yi,
           const float* __restrict__ w1,
           const float* __restrict__ b1,
           const float* __restrict__ w2,
           const float* __restrict__ b2,
           const float* __restrict__ w3,
           const float* __restrict__ b3,
           const float* __restrict__ Am,
           float* __restrict__ out,
           unsigned char* __restrict__ ws)
{
  extern __shared__ unsigned short smem[];
  __shared__ int g_ok;
  unsigned short* w2s  = smem + OFF_W2;
  unsigned short* w1s  = smem + OFF_W1;
  unsigned short* w3s  = smem + OFF_W3;
  unsigned short* Asl  = smem + OFF_A;
  unsigned short* h1sl = smem + OFF_H1;
  unsigned short* h2sl = smem + OFF_H2;
  unsigned short* ysl  = smem + OFF_Y;
  float* fregion = (float*)((char*)smem + FREG_BYTE);
  float* partial = fregion;          // 4 x 16 x 16
  float* b1s = fregion + 1024;       // 64
  float* b2s = fregion + 1088;       // 64
  float* b3s = fregion + 1152;       // 16

  const int tid  = threadIdx.x;
  const int wid  = tid >> 6;
  const int lane = tid & 63;
  const int l16  = lane & 15;
  const int quad = lane >> 4;
  const int koff = quad * 8;

  const int blk = blockIdx.x;
  const int g = blk >> 3;       // group
  const int p = blk & 7;        // wg within group
  const int hp = p * 64;        // hidden slice base
  const int dp = p * 16;        // D slice base
  const int b0 = g * MROW;      // batch row base

  unsigned* bar = (unsigned*)ws + (size_t)g * 16;
  unsigned short* h1g = (unsigned short*)(ws + 4096);
  unsigned short* h2g = h1g + NGRP * MROW * Ww;
  float* kg = (float*)(h2g + NGRP * MROW * Ww);

  // ---- stage weights into LDS as bf16 (read from HBM exactly once) ----
  for (int i = tid; i < 64 * 32; i += NTHR) {           // w1: 64 x 128
    int r = i >> 5, c = (i & 31) * 4;
    st4bf(w1s + r * 136 + c, *(const float4*)(w1 + (hp + r) * Dd + c));
  }
  for (int i = tid; i < 64 * 128; i += NTHR) {          // w2: 64 x 512
    int r = i >> 7, c = (i & 127) * 4;
    st4bf(w2s + r * 520 + c, *(const float4*)(w2 + (hp + r) * Ww + c));
  }
  for (int i = tid; i < 16 * 128; i += NTHR) {          // w3: 16 x 512
    int r = i >> 7, c = (i & 127) * 4;
    st4bf(w3s + r * 520 + c, *(const float4*)(w3 + (dp + r) * Ww + c));
  }
  for (int i = tid; i < 16 * 32; i += NTHR) {           // A: 16 x 128
    int r = i >> 5, c = (i & 31) * 4;
    st4bf(Asl + r * 136 + c, *(const float4*)(Am + (dp + r) * Dd + c));
  }
  if (tid < 64)       b1s[tid]       = b1[hp + tid];
  else if (tid < 128) b2s[tid - 64]  = b2[hp + tid - 64];
  else if (tid < 144) b3s[tid - 128] = b3[dp + tid - 128];

  // ---- y0: fp32 regs (8 elems/thread), ysl bf16, out[t=0] fp32 ----
  const int yr = tid >> 4;
  const int yc = (tid & 15) * 8;
  float y[8];
  {
    float4 v0 = *(const float4*)(yi + (b0 + yr) * Dd + yc);
    float4 v1 = *(const float4*)(yi + (b0 + yr) * Dd + yc + 4);
    y[0] = v0.x; y[1] = v0.y; y[2] = v0.z; y[3] = v0.w;
    y[4] = v1.x; y[5] = v1.y; y[6] = v1.z; y[7] = v1.w;
    st4bf(ysl + yr * 136 + yc, v0);
    st4bf(ysl + yr * 136 + yc + 4, v1);
    if (p == 0) {
      *(float4*)(out + (size_t)(b0 + yr) * (Tt * Dd) + yc) = v0;
      *(float4*)(out + (size_t)(b0 + yr) * (Tt * Dd) + yc + 4) = v1;
    }
  }
  __syncthreads();

  const float ATAB[5][5] = {
    {0.161f, 0.f, 0.f, 0.f, 0.f},
    {-0.008480655492356989f, 0.335480655492357f, 0.f, 0.f, 0.f},
    {2.8971530571054935f, -6.359448489975075f, 4.3622954328695815f, 0.f, 0.f},
    {5.325864828439257f, -11.748883564062828f, 7.4955393428898365f,
     -0.09249506636175525f, 0.f},
    {5.86145544294642f, -12.92096931784711f, 8.159367898576159f,
     -0.071584973281401f, -0.028269050394068383f}};
  const float BTAB[6] = {0.09646076681806523f, 0.01f, 0.4798896504144996f,
                         1.379008574103742f, -3.290069515436081f,
                         2.324710524099774f};

  unsigned tgt = 0;
  bool alive = true;

  for (int t = 0; t < NSTEP && alive; ++t) {
    float hdt = ts[t + 1] - ts[t];
    float kreg[6][8];

    #pragma unroll
    for (int s = 0; s < 6; ++s) {
      // ---------------- phase 1: h1 slice = tanh(y @ w1s^T + b1) ----------
      {
        f32x4 acc = {0.f, 0.f, 0.f, 0.f};
        const unsigned short* ap = ysl + l16 * 136 + koff;
        const unsigned short* bp = w1s + (wid * 16 + l16) * 136 + koff;
        #pragma unroll
        for (int kt = 0; kt < 4; ++kt)
          acc = __builtin_amdgcn_mfma_f32_16x16x32_bf16(
              *(const bf16x8*)(ap + kt * 32), *(const bf16x8*)(bp + kt * 32),
              acc, 0, 0, 0);
        float bias = b1s[wid * 16 + l16];
        int colg = hp + wid * 16 + l16;
        #pragma unroll
        for (int r = 0; r < 4; ++r) {
          int m = quad * 4 + r;
          h1g[(unsigned)(g * MROW + m) * Ww + colg] =
              f2b(fast_tanh(acc[r] + bias));
        }
      }
      tgt += PWG;
      alive = group_barrier(bar, tgt, &g_ok);
      if (!alive) break;
      { // gather full h1 into LDS
        int r = tid >> 4, c = (tid & 15) * 32;
        const uint4* sp = (const uint4*)(h1g + (unsigned)(g * MROW + r) * Ww + c);
        uint4* dq = (uint4*)(h1sl + r * 520 + c);
        dq[0] = sp[0]; dq[1] = sp[1]; dq[2] = sp[2]; dq[3] = sp[3];
      }
      __syncthreads();

      // ---------------- phase 2: h2 slice = tanh(h1 @ w2s^T + b2) ---------
      {
        f32x4 acc = {0.f, 0.f, 0.f, 0.f};
        const unsigned short* ap = h1sl + l16 * 520 + koff;
        const unsigned short* bp = w2s + (wid * 16 + l16) * 520 + koff;
        #pragma unroll
        for (int kt = 0; kt < 16; ++kt)
          acc = __builtin_amdgcn_mfma_f32_16x16x32_bf16(
              *(const bf16x8*)(ap + kt * 32), *(const bf16x8*)(bp + kt * 32),
              acc, 0, 0, 0);
        float bias = b2s[wid * 16 + l16];
        int colg = hp + wid * 16 + l16;
        #pragma unroll
        for (int r = 0; r < 4; ++r) {
          int m = quad * 4 + r;
          h2g[(unsigned)(g * MROW + m) * Ww + colg] =
              f2b(fast_tanh(acc[r] + bias));
        }
      }
      tgt += PWG;
      alive = group_barrier(bar, tgt, &g_ok);
      if (!alive) break;
      { // gather full h2 into LDS
        int r = tid >> 4, c = (tid & 15) * 32;
        const uint4* sp = (const uint4*)(h2g + (unsigned)(g * MROW + r) * Ww + c);
        uint4* dq = (uint4*)(h2sl + r * 520 + c);
        dq[0] = sp[0]; dq[1] = sp[1]; dq[2] = sp[2]; dq[3] = sp[3];
      }
      __syncthreads();

      // ---------------- phase 3: k slice = h2 @ w3s^T + b3 + y @ As^T -----
      {
        f32x4 acc = {0.f, 0.f, 0.f, 0.f};
        const unsigned short* ap = h2sl + l16 * 520 + koff;
        const unsigned short* bp = w3s + l16 * 520 + koff;
        #pragma unroll
        for (int kk = 0; kk < 4; ++kk) {  // wave-split K over w3 (128 each)
          int kt = wid * 4 + kk;
          acc = __builtin_amdgcn_mfma_f32_16x16x32_bf16(
              *(const bf16x8*)(ap + kt * 32), *(const bf16x8*)(bp + kt * 32),
              acc, 0, 0, 0);
        }
        acc = __builtin_amdgcn_mfma_f32_16x16x32_bf16(   // wave-split K over A
            *(const bf16x8*)(ysl + l16 * 136 + wid * 32 + koff),
            *(const bf16x8*)(Asl + l16 * 136 + wid * 32 + koff),
            acc, 0, 0, 0);
        #pragma unroll
        for (int r = 0; r < 4; ++r)
          partial[wid * 256 + (quad * 4 + r) * 16 + l16] = acc[r];
      }
      __syncthreads();
      { // cross-wave K reduction + bias, write k slice to workspace
        int m = tid >> 4, n = tid & 15;
        float sum = partial[m * 16 + n] + partial[256 + m * 16 + n] +
                    partial[512 + m * 16 + n] + partial[768 + m * 16 + n] +
                    b3s[n];
        kg[(unsigned)(g * MROW + m) * Dd + dp + n] = sum;
      }
      tgt += PWG;
      alive = group_barrier(bar, tgt, &g_ok);
      if (!alive) break;

      // ---------------- phase 4: RK combine (fp32 registers) --------------
      {
        const float4* kp4 =
            (const float4*)(kg + (unsigned)(g * MROW + yr) * Dd + yc);
        float4 ka = kp4[0], kb = kp4[1];
        kreg[s][0] = ka.x; kreg[s][1] = ka.y; kreg[s][2] = ka.z; kreg[s][3] = ka.w;
        kreg[s][4] = kb.x; kreg[s][5] = kb.y; kreg[s][6] = kb.z; kreg[s][7] = kb.w;
        float a[8];
        if (s < 5) {
          #pragma unroll
          for (int j = 0; j < 8; ++j) {
            float v = y[j];
            #pragma unroll
            for (int q = 0; q <= s; ++q) v += hdt * ATAB[s][q] * kreg[q][j];
            a[j] = v;
          }
        } else {
          #pragma unroll
          for (int j = 0; j < 8; ++j) {
            float v = y[j];
            #pragma unroll
            for (int q = 0; q < 6; ++q) v += hdt * BTAB[q] * kreg[q][j];
            y[j] = v; a[j] = v;
          }
        }
        float4 v0 = {a[0], a[1], a[2], a[3]};
        float4 v1 = {a[4], a[5], a[6], a[7]};
        st4bf(ysl + yr * 136 + yc, v0);
        st4bf(ysl + yr * 136 + yc + 4, v1);
        if (s == 5 && p == 0) {
          float* op = out + (size_t)(b0 + yr) * (Tt * Dd) +
                      (size_t)(t + 1) * Dd + yc;
          *(float4*)op = v0;
          *(float4*)(op + 4) = v1;
        }
      }
      __syncthreads();
    } // stages
  } // steps
}

extern "C" void kernel_launch(void* const* d_in, const int* in_sizes, int n_in,
                              void* d_out, int out_size, void* d_ws, size_t ws_size,
                              hipStream_t stream) {
  (void)in_sizes; (void)n_in; (void)out_size; (void)ws_size;

  const float* ts = (const float*)d_in[0];
  const float* yi = (const float*)d_in[1];
  const float* w1 = (const float*)d_in[2];
  const float* b1 = (const float*)d_in[3];
  const float* w2 = (const float*)d_in[4];
  const float* b2 = (const float*)d_in[5];
  const float* w3 = (const float*)d_in[6];
  const float* b3 = (const float*)d_in[7];
  const float* Am = (const float*)d_in[8];
  float* outp = (float*)d_out;
  unsigned char* wsp = (unsigned char*)d_ws;

  (void)hipFuncSetAttribute(reinterpret_cast<const void*>(ode_kernel),
                            hipFuncAttributeMaxDynamicSharedMemorySize,
                            SMEM_BYTES);

  init_ws_kernel<<<1, 1024, 0, stream>>>((unsigned*)d_ws);

  void* args[] = {&ts, &yi, &w1, &b1, &w2, &b2, &w3, &b3, &Am, &outp, &wsp};
  hipError_t e = hipLaunchCooperativeKernel(ode_kernel, dim3(NGRP * PWG),
                                            dim3(NTHR), args,
                                            (unsigned)SMEM_BYTES, stream);
  if (e != hipSuccess) {
    // Fallback: plain launch (256 blocks at 1/CU are co-resident in practice)
    ode_kernel<<<dim3(NGRP * PWG), dim3(NTHR), SMEM_BYTES, stream>>>(
        ts, yi, w1, b1, w2, b2, w3, b3, Am, outp, wsp);
  }
}

// Round 3
// 50624.796 us; speedup vs baseline: 3.0858x; 3.0858x over previous
//
#include <hip/hip_runtime.h>
#include <stdint.h>

// ---------------------------------------------------------------------------
// StabilizedNeuralODE: 6-stage RK over 511 steps of a 128->512->512->128 MLP
// vector field (+ y@A.T). Inputs/outputs fp32; internal GEMMs bf16 MFMA with
// fp32 accumulation; y / k / RK combine stay fp32.
//
// Design: 32 groups x 8 WGs (256 WGs, 1 per CU, cooperative launch).
//  - Group g owns batch rows [16g, 16g+16) for the entire trajectory.
//  - WG p of a group keeps bf16 weight slices LDS-resident (~100 KB).
//  - Per RK stage: 3 phases (h1, h2, k). Cross-WG handoff goes through an
//    L3-resident workspace using RELAXED agent-scope atomics only (sc1 ops,
//    coherent at Infinity Cache). NO acquire/release fences: R2 showed those
//    compile to buffer_wbl2/buffer_inv (full L2 flush+inv) -> 19 GB of HBM
//    traffic and 17 us/phase. Ordering = per-wave s_waitcnt vmcnt(0) before
//    the flag increment; readers' sc1 loads can never see stale cache.
// MFMA: v_mfma_f32_16x16x32_bf16. A-frag: A[m=lane&15][k=quad*8+j];
// B-frag: B[n=lane&15][k=quad*8+j]; C/D: n=lane&15, m=quad*4+reg.
// ---------------------------------------------------------------------------

#define Dd 128
#define Ww 512
#define Tt 512
#define NSTEP 511
#define NGRP 32
#define PWG 8
#define MROW 16
#define NTHR 256

// LDS layout (ushort element offsets)
#define OFF_W2 0        // 64 x 520
#define OFF_W1 33280    // 64 x 136
#define OFF_W3 41984    // 16 x 520
#define OFF_A  50304    // 16 x 136
#define OFF_H1 52480    // 16 x 520
#define OFF_H2 60800    // 16 x 520
#define OFF_Y  69120    // 16 x 136
#define FREG_BYTE 142592
#define SMEM_BYTES 147456

typedef __attribute__((ext_vector_type(8))) __bf16 bf16x8;
typedef __attribute__((ext_vector_type(4))) float f32x4;
typedef unsigned long long u64;

__device__ __forceinline__ unsigned short f2b(float f) {
  union { float f; unsigned int u; } v; v.f = f;
  return (unsigned short)((v.u + 0x7fffu + ((v.u >> 16) & 1u)) >> 16);
}
__device__ __forceinline__ void st4bf(unsigned short* dst, float4 v) {
  union { unsigned short u[4]; uint2 q; } p;
  p.u[0] = f2b(v.x); p.u[1] = f2b(v.y); p.u[2] = f2b(v.z); p.u[3] = f2b(v.w);
  *(uint2*)dst = p.q;
}
__device__ __forceinline__ u64 pack4bf(float4 v) {
  union { unsigned short u[4]; u64 q; } p;
  p.u[0] = f2b(v.x); p.u[1] = f2b(v.y); p.u[2] = f2b(v.z); p.u[3] = f2b(v.w);
  return p.q;
}
__device__ __forceinline__ float fast_tanh(float x) {
  x = fminf(fmaxf(x, -15.f), 15.f);
  float e = __expf(2.f * x);
  return (e - 1.f) / (e + 1.f);
}

// sc1 (coherent-point) accesses: relaxed agent-scope atomics. No fences.
__device__ __forceinline__ void stg_c_u64(u64* p, u64 v) {
  __hip_atomic_store(p, v, __ATOMIC_RELAXED, __HIP_MEMORY_SCOPE_AGENT);
}
__device__ __forceinline__ u64 ldg_c_u64(const u64* p) {
  return __hip_atomic_load((u64*)p, __ATOMIC_RELAXED, __HIP_MEMORY_SCOPE_AGENT);
}
__device__ __forceinline__ void stg_c_f32(float* p, float v) {
  __hip_atomic_store(p, v, __ATOMIC_RELAXED, __HIP_MEMORY_SCOPE_AGENT);
}

// Group barrier: monotone counter, relaxed fetch_add + relaxed spin.
// Explicit per-wave vmcnt(0) drain before syncthreads guarantees all sc1
// data stores reached the coherence point before the flag increment.
// Bounded spin -> uniform bail (loud failure instead of hang).
__device__ __forceinline__ bool group_barrier(unsigned* bar, unsigned target,
                                              int* okf) {
  __builtin_amdgcn_s_waitcnt(0x0F70);   // vmcnt(0) only
  __syncthreads();
  if (threadIdx.x == 0) {
    int ok = 1;
    __hip_atomic_fetch_add(&bar[0], 1u, __ATOMIC_RELAXED,
                           __HIP_MEMORY_SCOPE_AGENT);
    unsigned spins = 0;
    while (__hip_atomic_load(&bar[0], __ATOMIC_RELAXED,
                             __HIP_MEMORY_SCOPE_AGENT) < target) {
      __builtin_amdgcn_s_sleep(1);
      if (++spins > (1u << 18)) { ok = 0; break; }
    }
    *okf = ok;
  }
  __syncthreads();
  return *okf != 0;
}

__global__ void init_ws_kernel(unsigned* ws) {
  ws[blockIdx.x * 1024 + threadIdx.x] = 0u;  // zero 8 KB barrier region
}

__global__ void __launch_bounds__(NTHR, 1)
ode_kernel(const float* __restrict__ ts,
           const float* __restrict__ yi,
           const float* __restrict__ w1,
           const float* __restrict__ b1,
           const float* __restrict__ w2,
           const float* __restrict__ b2,
           const float* __restrict__ w3,
           const float* __restrict__ b3,
           const float* __restrict__ Am,
           float* __restrict__ out,
           unsigned char* __restrict__ ws)
{
  extern __shared__ unsigned short smem[];
  __shared__ int g_ok;
  unsigned short* w2s  = smem + OFF_W2;
  unsigned short* w1s  = smem + OFF_W1;
  unsigned short* w3s  = smem + OFF_W3;
  unsigned short* Asl  = smem + OFF_A;
  unsigned short* h1sl = smem + OFF_H1;
  unsigned short* h2sl = smem + OFF_H2;
  unsigned short* ysl  = smem + OFF_Y;
  float* fregion = (float*)((char*)smem + FREG_BYTE);
  float* partial = fregion;          // 1024 floats: staging tile 16x64
  float* b1s = fregion + 1024;       // 64
  float* b2s = fregion + 1088;       // 64
  float* b3s = fregion + 1152;       // 16

  const int tid  = threadIdx.x;
  const int wid  = tid >> 6;
  const int lane = tid & 63;
  const int l16  = lane & 15;
  const int quad = lane >> 4;
  const int koff = quad * 8;

  const int blk = blockIdx.x;
  const int g = blk >> 3;       // group
  const int p = blk & 7;        // wg within group
  const int hp = p * 64;        // hidden slice base
  const int dp = p * 16;        // D slice base
  const int b0 = g * MROW;      // batch row base

  unsigned* bar = (unsigned*)ws + (size_t)g * 64;      // 256 B apart
  unsigned short* h1g = (unsigned short*)(ws + 8192);
  unsigned short* h2g = h1g + NGRP * MROW * Ww;
  float* kg = (float*)(h2g + NGRP * MROW * Ww);

  // ---- stage weights into LDS as bf16 (HBM read exactly once) ----
  for (int i = tid; i < 64 * 32; i += NTHR) {           // w1: 64 x 128
    int r = i >> 5, c = (i & 31) * 4;
    st4bf(w1s + r * 136 + c, *(const float4*)(w1 + (hp + r) * Dd + c));
  }
  for (int i = tid; i < 64 * 128; i += NTHR) {          // w2: 64 x 512
    int r = i >> 7, c = (i & 127) * 4;
    st4bf(w2s + r * 520 + c, *(const float4*)(w2 + (hp + r) * Ww + c));
  }
  for (int i = tid; i < 16 * 128; i += NTHR) {          // w3: 16 x 512
    int r = i >> 7, c = (i & 127) * 4;
    st4bf(w3s + r * 520 + c, *(const float4*)(w3 + (dp + r) * Ww + c));
  }
  for (int i = tid; i < 16 * 32; i += NTHR) {           // A: 16 x 128
    int r = i >> 5, c = (i & 31) * 4;
    st4bf(Asl + r * 136 + c, *(const float4*)(Am + (dp + r) * Dd + c));
  }
  if (tid < 64)       b1s[tid]       = b1[hp + tid];
  else if (tid < 128) b2s[tid - 64]  = b2[hp + tid - 64];
  else if (tid < 144) b3s[tid - 128] = b3[dp + tid - 128];

  // ---- y0: fp32 regs (8/thread), ysl bf16, out[t=0] fp32 ----
  const int yr = tid >> 4;
  const int yc = (tid & 15) * 8;
  float y[8];
  {
    float4 v0 = *(const float4*)(yi + (b0 + yr) * Dd + yc);
    float4 v1 = *(const float4*)(yi + (b0 + yr) * Dd + yc + 4);
    y[0] = v0.x; y[1] = v0.y; y[2] = v0.z; y[3] = v0.w;
    y[4] = v1.x; y[5] = v1.y; y[6] = v1.z; y[7] = v1.w;
    st4bf(ysl + yr * 136 + yc, v0);
    st4bf(ysl + yr * 136 + yc + 4, v1);
    if (p == 0) {
      *(float4*)(out + (size_t)(b0 + yr) * (Tt * Dd) + yc) = v0;
      *(float4*)(out + (size_t)(b0 + yr) * (Tt * Dd) + yc + 4) = v1;
    }
  }
  __syncthreads();

  const float ATAB[5][5] = {
    {0.161f, 0.f, 0.f, 0.f, 0.f},
    {-0.008480655492356989f, 0.335480655492357f, 0.f, 0.f, 0.f},
    {2.8971530571054935f, -6.359448489975075f, 4.3622954328695815f, 0.f, 0.f},
    {5.325864828439257f, -11.748883564062828f, 7.4955393428898365f,
     -0.09249506636175525f, 0.f},
    {5.86145544294642f, -12.92096931784711f, 8.159367898576159f,
     -0.071584973281401f, -0.028269050394068383f}};
  const float BTAB[6] = {0.09646076681806523f, 0.01f, 0.4798896504144996f,
                         1.379008574103742f, -3.290069515436081f,
                         2.324710524099774f};

  unsigned tgt = 0;
  bool alive = true;

  for (int t = 0; t < NSTEP && alive; ++t) {
    float hdt = ts[t + 1] - ts[t];
    float kreg[6][8];

    #pragma unroll
    for (int s = 0; s < 6; ++s) {
      // -------- phase 1: h1 slice = tanh(y @ w1s^T + b1), cols [hp,hp+64) --
      {
        f32x4 acc = {0.f, 0.f, 0.f, 0.f};
        const unsigned short* ap = ysl + l16 * 136 + koff;
        const unsigned short* bp = w1s + (wid * 16 + l16) * 136 + koff;
        #pragma unroll
        for (int kt = 0; kt < 4; ++kt)
          acc = __builtin_amdgcn_mfma_f32_16x16x32_bf16(
              *(const bf16x8*)(ap + kt * 32), *(const bf16x8*)(bp + kt * 32),
              acc, 0, 0, 0);
        float bias = b1s[wid * 16 + l16];
        #pragma unroll
        for (int r = 0; r < 4; ++r)
          partial[(quad * 4 + r) * 64 + wid * 16 + l16] =
              fast_tanh(acc[r] + bias);
      }
      __syncthreads();
      { // pack + coalesced sc1 store of the 16x64 slice
        int row = tid >> 4, c4 = (tid & 15) * 4;
        float4 v = *(const float4*)&partial[row * 64 + c4];
        stg_c_u64((u64*)(h1g + (unsigned)(g * MROW + row) * Ww + hp + c4),
                  pack4bf(v));
      }
      tgt += PWG;
      alive = group_barrier(bar, tgt, &g_ok);
      if (!alive) break;
      { // gather full h1 (16x512) into LDS via sc1 loads
        int r = tid >> 4, cb = (tid & 15) * 4;
        #pragma unroll
        for (int j = 0; j < 8; ++j) {
          int c = cb + j * 64;
          u64 d = ldg_c_u64((const u64*)(h1g + (unsigned)(g * MROW + r) * Ww + c));
          *(u64*)(h1sl + r * 520 + c) = d;
        }
      }
      __syncthreads();

      // -------- phase 2: h2 slice = tanh(h1 @ w2s^T + b2) ------------------
      {
        f32x4 acc = {0.f, 0.f, 0.f, 0.f};
        const unsigned short* ap = h1sl + l16 * 520 + koff;
        const unsigned short* bp = w2s + (wid * 16 + l16) * 520 + koff;
        #pragma unroll
        for (int kt = 0; kt < 16; ++kt)
          acc = __builtin_amdgcn_mfma_f32_16x16x32_bf16(
              *(const bf16x8*)(ap + kt * 32), *(const bf16x8*)(bp + kt * 32),
              acc, 0, 0, 0);
        float bias = b2s[wid * 16 + l16];
        #pragma unroll
        for (int r = 0; r < 4; ++r)
          partial[(quad * 4 + r) * 64 + wid * 16 + l16] =
              fast_tanh(acc[r] + bias);
      }
      __syncthreads();
      {
        int row = tid >> 4, c4 = (tid & 15) * 4;
        float4 v = *(const float4*)&partial[row * 64 + c4];
        stg_c_u64((u64*)(h2g + (unsigned)(g * MROW + row) * Ww + hp + c4),
                  pack4bf(v));
      }
      tgt += PWG;
      alive = group_barrier(bar, tgt, &g_ok);
      if (!alive) break;
      {
        int r = tid >> 4, cb = (tid & 15) * 4;
        #pragma unroll
        for (int j = 0; j < 8; ++j) {
          int c = cb + j * 64;
          u64 d = ldg_c_u64((const u64*)(h2g + (unsigned)(g * MROW + r) * Ww + c));
          *(u64*)(h2sl + r * 520 + c) = d;
        }
      }
      __syncthreads();

      // -------- phase 3: k slice = h2 @ w3s^T + b3 + y @ As^T --------------
      {
        f32x4 acc = {0.f, 0.f, 0.f, 0.f};
        const unsigned short* ap = h2sl + l16 * 520 + koff;
        const unsigned short* bp = w3s + l16 * 520 + koff;
        #pragma unroll
        for (int kk = 0; kk < 4; ++kk) {  // wave-split K over w3 (128 each)
          int kt = wid * 4 + kk;
          acc = __builtin_amdgcn_mfma_f32_16x16x32_bf16(
              *(const bf16x8*)(ap + kt * 32), *(const bf16x8*)(bp + kt * 32),
              acc, 0, 0, 0);
        }
        acc = __builtin_amdgcn_mfma_f32_16x16x32_bf16(   // wave-split K over A
            *(const bf16x8*)(ysl + l16 * 136 + wid * 32 + koff),
            *(const bf16x8*)(Asl + l16 * 136 + wid * 32 + koff),
            acc, 0, 0, 0);
        #pragma unroll
        for (int r = 0; r < 4; ++r)
          partial[wid * 256 + (quad * 4 + r) * 16 + l16] = acc[r];
      }
      __syncthreads();
      { // cross-wave K reduction + bias; sc1 store k slice (fp32)
        int m = tid >> 4, n = tid & 15;
        float sum = partial[m * 16 + n] + partial[256 + m * 16 + n] +
                    partial[512 + m * 16 + n] + partial[768 + m * 16 + n] +
                    b3s[n];
        stg_c_f32(kg + (unsigned)(g * MROW + m) * Dd + dp + n, sum);
      }
      tgt += PWG;
      alive = group_barrier(bar, tgt, &g_ok);
      if (!alive) break;

      // -------- phase 4: RK combine (fp32 registers, redundant per WG) -----
      {
        union { u64 q[4]; float f[8]; } kk;
        const u64* kp = (const u64*)(kg + (unsigned)(g * MROW + yr) * Dd + yc);
        #pragma unroll
        for (int j = 0; j < 4; ++j) kk.q[j] = ldg_c_u64(kp + j);
        #pragma unroll
        for (int j = 0; j < 8; ++j) kreg[s][j] = kk.f[j];

        float a[8];
        if (s < 5) {
          #pragma unroll
          for (int j = 0; j < 8; ++j) {
            float v = y[j];
            #pragma unroll
            for (int q = 0; q <= s; ++q) v += hdt * ATAB[s][q] * kreg[q][j];
            a[j] = v;
          }
        } else {
          #pragma unroll
          for (int j = 0; j < 8; ++j) {
            float v = y[j];
            #pragma unroll
            for (int q = 0; q < 6; ++q) v += hdt * BTAB[q] * kreg[q][j];
            y[j] = v; a[j] = v;
          }
        }
        float4 v0 = {a[0], a[1], a[2], a[3]};
        float4 v1 = {a[4], a[5], a[6], a[7]};
        st4bf(ysl + yr * 136 + yc, v0);
        st4bf(ysl + yr * 136 + yc + 4, v1);
        if (s == 5 && p == 0) {
          float* op = out + (size_t)(b0 + yr) * (Tt * Dd) +
                      (size_t)(t + 1) * Dd + yc;
          *(float4*)op = v0;
          *(float4*)(op + 4) = v1;
        }
      }
      __syncthreads();
    } // stages
  } // steps
}

extern "C" void kernel_launch(void* const* d_in, const int* in_sizes, int n_in,
                              void* d_out, int out_size, void* d_ws, size_t ws_size,
                              hipStream_t stream) {
  (void)in_sizes; (void)n_in; (void)out_size; (void)ws_size;

  const float* ts = (const float*)d_in[0];
  const float* yi = (const float*)d_in[1];
  const float* w1 = (const float*)d_in[2];
  const float* b1 = (const float*)d_in[3];
  const float* w2 = (const float*)d_in[4];
  const float* b2 = (const float*)d_in[5];
  const float* w3 = (const float*)d_in[6];
  const float* b3 = (const float*)d_in[7];
  const float* Am = (const float*)d_in[8];
  float* outp = (float*)d_out;
  unsigned char* wsp = (unsigned char*)d_ws;

  (void)hipFuncSetAttribute(reinterpret_cast<const void*>(ode_kernel),
                            hipFuncAttributeMaxDynamicSharedMemorySize,
                            SMEM_BYTES);

  init_ws_kernel<<<2, 1024, 0, stream>>>((unsigned*)d_ws);

  void* args[] = {&ts, &yi, &w1, &b1, &w2, &b2, &w3, &b3, &Am, &outp, &wsp};
  hipError_t e = hipLaunchCooperativeKernel(ode_kernel, dim3(NGRP * PWG),
                                            dim3(NTHR), args,
                                            (unsigned)SMEM_BYTES, stream);
  if (e != hipSuccess) {
    // Fallback: plain launch (256 blocks at 1/CU are co-resident in practice)
    ode_kernel<<<dim3(NGRP * PWG), dim3(NTHR), SMEM_BYTES, stream>>>(
        ts, yi, w1, b1, w2, b2, w3, b3, Am, outp, wsp);
  }
}